// Round 2
// baseline (1149.443 us; speedup 1.0000x reference)
//
#include <hip/hip_runtime.h>
#include <hip/hip_bf16.h>
#include <math.h>

#define NNODES 50000
#define NEDGES 800000
#define EPTOT  (NEDGES + NNODES)   // 850000 edges incl self-loops
#define NEG_SLOPE 0.2f
#define BN_EPS 1e-5f

// ---------------- CSR build ----------------

__global__ void count_deg(const int* __restrict__ ei, int* __restrict__ deg){
    int e = blockIdx.x * blockDim.x + threadIdx.x;
    if (e >= EPTOT) return;
    int dst = (e < NEDGES) ? ei[NEDGES + e] : (e - NEDGES);
    atomicAdd(&deg[dst], 1);
}

__global__ void scan1(const int* __restrict__ deg, int* __restrict__ offs, int* __restrict__ bsum){
    __shared__ int s[1024];
    int t = threadIdx.x;
    int i = blockIdx.x * 1024 + t;
    int v = (i < NNODES) ? deg[i] : 0;
    s[t] = v;
    for (int o = 1; o < 1024; o <<= 1){
        __syncthreads();
        int x = (t >= o) ? s[t - o] : 0;
        __syncthreads();
        s[t] += x;
    }
    if (i < NNODES) offs[i] = s[t] - v;     // exclusive, block-local
    if (t == 1023) bsum[blockIdx.x] = s[1023];
}

__global__ void scan2(const int* __restrict__ bsum, int* __restrict__ bbase, int* __restrict__ offs){
    if (threadIdx.x == 0 && blockIdx.x == 0){
        int run = 0;
        for (int b = 0; b < 49; ++b){ bbase[b] = run; run += bsum[b]; }
        offs[NNODES] = EPTOT;
    }
}

__global__ void scan3(int* __restrict__ offs, const int* __restrict__ bbase, int* __restrict__ cursor){
    int i = blockIdx.x * 1024 + threadIdx.x;
    if (i < NNODES){
        int v = offs[i] + bbase[blockIdx.x];
        offs[i] = v;
        cursor[i] = v;
    }
}

__global__ void scatter_edges(const int* __restrict__ ei, int* __restrict__ cursor, int* __restrict__ esrc){
    int e = blockIdx.x * blockDim.x + threadIdx.x;
    if (e >= EPTOT) return;
    int s, d;
    if (e < NEDGES){ s = ei[e]; d = ei[NEDGES + e]; } else { s = d = e - NEDGES; }
    int pos = atomicAdd(&cursor[d], 1);
    esrc[pos] = s;
}

// ---------------- GEMM: out[N x DTOT] = A[N x 128] @ B[128 x DTOT] + bias ----------------
// 32 rows x 64 cols per block, 256 threads, fp32 accum, LDS-staged A tile + B tile.

template<int DTOT>
__global__ __launch_bounds__(256) void gemm_bias(const float* __restrict__ A, const float* __restrict__ B,
                                                 const float* __restrict__ bias, float* __restrict__ out){
    __shared__ float Bs[128 * 64];   // [k][c] 32 KB
    __shared__ float As[32 * 128];   // [r][k] 16 KB
    int t  = threadIdx.x;
    int c0 = blockIdx.y * 64;
    int r0 = blockIdx.x * 32;

    for (int i = t; i < 128 * 64; i += 256){
        int k = i >> 6, c = i & 63;
        Bs[i] = B[k * DTOT + c0 + c];
    }
    for (int i = t; i < 32 * 128; i += 256){
        int r = i >> 7, k = i & 127;
        int row = r0 + r;
        As[i] = (row < NNODES) ? A[(size_t)row * 128 + k] : 0.f;
    }
    __syncthreads();

    int tx = t & 31;    // col pair index: cols 2*tx, 2*tx+1
    int ty = t >> 5;    // 0..7, rows ty + 8*j
    float acc[4][2] = {};
    const float2* Bs2 = (const float2*)Bs;
    #pragma unroll 4
    for (int k = 0; k < 128; ++k){
        float2 b = Bs2[k * 32 + tx];
        #pragma unroll
        for (int j = 0; j < 4; ++j){
            float a = As[(ty + 8 * j) * 128 + k];
            acc[j][0] += a * b.x;
            acc[j][1] += a * b.y;
        }
    }

    int c = c0 + 2 * tx;
    float bi0 = bias[c], bi1 = bias[c + 1];
    #pragma unroll
    for (int j = 0; j < 4; ++j){
        int r = r0 + ty + 8 * j;
        if (r < NNODES){
            out[(size_t)r * DTOT + c]     = acc[j][0] + bi0;
            out[(size_t)r * DTOT + c + 1] = acc[j][1] + bi1;
        }
    }
}

// ---------------- GATv2 per-node aggregation ----------------
// One block per destination node, 128 threads = 2 waves, wave = head.
// Lane handles VPT = C/64 channels. Logit reduction = 64-lane butterfly
// (wave-uniform result, no LDS, no global scratch). Pass 2 recomputes the
// logit bit-identically on the xl values it gathers anyway -> den >= 1.

template<int C>
__global__ __launch_bounds__(128) void gat_aggregate(
    const float* __restrict__ xl, const float* __restrict__ xr,
    const float* __restrict__ att, const int* __restrict__ offs,
    const int* __restrict__ esrc, float* __restrict__ out,
    const float* __restrict__ bias2, int mean_heads)
{
    constexpr int VPT = C / 64;
    constexpr int HC  = 2 * C;
    __shared__ float tmp[HC];
    int n    = blockIdx.x;
    int lane = threadIdx.x & 63;
    int head = threadIdx.x >> 6;
    size_t rowbase = (size_t)n * HC + head * C;

    float xrv[VPT], av[VPT];
    #pragma unroll
    for (int v = 0; v < VPT; ++v){
        xrv[v] = xr[rowbase + lane + 64 * v];
        av[v]  = att[head * C + lane + 64 * v];
    }
    int e0 = offs[n], e1 = offs[n + 1];

    // pass 1: running max of logits
    float m = -1e30f;
    for (int p = e0; p < e1; ++p){
        int s = esrc[p];
        size_t sb = (size_t)s * HC + head * C;
        float part = 0.f;
        #pragma unroll
        for (int v = 0; v < VPT; ++v){
            float u = xl[sb + lane + 64 * v] + xrv[v];
            u = (u > 0.f) ? u : NEG_SLOPE * u;
            part += u * av[v];
        }
        #pragma unroll
        for (int o = 32; o > 0; o >>= 1) part += __shfl_xor(part, o, 64);
        m = fmaxf(m, part);
    }

    // pass 2: softmax-weighted aggregation (recompute logit, identical fp ordering)
    float den = 0.f, acc[VPT] = {};
    for (int p = e0; p < e1; ++p){
        int s = esrc[p];
        size_t sb = (size_t)s * HC + head * C;
        float xlv[VPT], part = 0.f;
        #pragma unroll
        for (int v = 0; v < VPT; ++v){
            xlv[v] = xl[sb + lane + 64 * v];
            float u = xlv[v] + xrv[v];
            u = (u > 0.f) ? u : NEG_SLOPE * u;
            part += u * av[v];
        }
        #pragma unroll
        for (int o = 32; o > 0; o >>= 1) part += __shfl_xor(part, o, 64);
        float ex = __expf(part - m);
        den += ex;
        #pragma unroll
        for (int v = 0; v < VPT; ++v) acc[v] += ex * xlv[v];
    }
    float inv = 1.f / den;

    if (!mean_heads){
        #pragma unroll
        for (int v = 0; v < VPT; ++v) out[rowbase + lane + 64 * v] = acc[v] * inv;
    } else {
        #pragma unroll
        for (int v = 0; v < VPT; ++v) tmp[head * C + lane + 64 * v] = acc[v] * inv;
        __syncthreads();
        if (head == 0){
            #pragma unroll
            for (int v = 0; v < VPT; ++v){
                int c = lane + 64 * v;
                out[(size_t)n * C + c] = 0.5f * (tmp[c] + tmp[C + c]) + bias2[c];
            }
        }
    }
}

// ---------------- BatchNorm ----------------

template<int COLS>
__global__ void bn_stats(const float* __restrict__ x, float* __restrict__ sums, int stride){
    __shared__ float ls[512];
    int t = threadIdx.x;              // 256 threads
    int col = t % COLS;
    int rg  = t / COLS;
    const int RG = 256 / COLS;
    float s = 0.f, q = 0.f;
    for (int r = blockIdx.x * RG + rg; r < NNODES; r += gridDim.x * RG){
        float v = x[(size_t)r * stride + col];
        s += v; q += v * v;
    }
    ls[t] = s; ls[256 + t] = q;
    __syncthreads();
    if (rg == 0){
        for (int g = 1; g < RG; ++g){ s += ls[g * COLS + col]; q += ls[256 + g * COLS + col]; }
        atomicAdd(&sums[col], s);
        atomicAdd(&sums[COLS + col], q);
    }
}

__global__ void bn1_finalize(const float* __restrict__ sums, const float* __restrict__ gamma,
                             const float* __restrict__ beta, float* __restrict__ ss){
    int c = threadIdx.x;              // 128
    float mu  = sums[c] / (float)NNODES;
    float var = sums[128 + c] / (float)NNODES - mu * mu;
    float sc  = gamma[c] * rsqrtf(var + BN_EPS);
    ss[c]       = sc;
    ss[128 + c] = beta[c] - mu * sc;
}

__global__ void bn_apply_relu(const float* __restrict__ o1, const float* __restrict__ ss,
                              float* __restrict__ h){
    int i = blockIdx.x * blockDim.x + threadIdx.x;
    if (i >= NNODES * 128) return;
    int c = i & 127;
    float v = o1[i] * ss[c] + ss[128 + c];
    h[i] = v > 0.f ? v : 0.f;
}

__global__ void bn2_finalize(const float* __restrict__ sums, float* __restrict__ ms){
    int c = threadIdx.x;              // 64
    float mu  = sums[c] / (float)NNODES;
    float var = sums[64 + c] / (float)NNODES - mu * mu;
    ms[c]      = mu;
    ms[64 + c] = rsqrtf(var + BN_EPS);
}

__global__ void final_out(const float* __restrict__ o2, const float* __restrict__ ms,
                          float* __restrict__ out){
    int i = blockIdx.x * blockDim.x + threadIdx.x;
    if (i >= NNODES * 128) return;
    int c = i & 127;
    float v = o2[i];
    float r;
    if (c < 64){
        r = (v - ms[c]) * ms[64 + c];           // BN, affine=False
    } else {
        r = (v > 20.f) ? v : log1pf(__expf(v)); // softplus
    }
    out[i] = r;
}

// ---------------- launch ----------------

extern "C" void kernel_launch(void* const* d_in, const int* in_sizes, int n_in,
                              void* d_out, int out_size, void* d_ws, size_t ws_size,
                              hipStream_t stream) {
    const float* x     = (const float*)d_in[0];
    const int*   ei    = (const int*)d_in[1];
    const float* W_l1  = (const float*)d_in[2];
    const float* b_l1  = (const float*)d_in[3];
    const float* W_r1  = (const float*)d_in[4];
    const float* b_r1  = (const float*)d_in[5];
    const float* att1  = (const float*)d_in[6];
    // d_in[7] = bias1: cancels through BN1 (constant per-column shift) -> unused
    const float* gamma1 = (const float*)d_in[8];
    const float* beta1  = (const float*)d_in[9];
    const float* W_l2  = (const float*)d_in[10];
    const float* b_l2  = (const float*)d_in[11];
    const float* W_r2  = (const float*)d_in[12];
    const float* b_r2  = (const float*)d_in[13];
    const float* att2  = (const float*)d_in[14];
    const float* bias2 = (const float*)d_in[15];
    float* out = (float*)d_out;

    char* w = (char*)d_ws;
    size_t off = 0;
    auto alloc = [&](size_t bytes) -> void* {
        void* p = w + off;
        off += (bytes + 255) & ~(size_t)255;
        return p;
    };
    const size_t NF = (size_t)NNODES * 128 * 4;   // 25.6 MB, 256-aligned
    float* xl1   = (float*)alloc(NF);   // [A0]
    float* xr1   = (float*)alloc(NF);   // [A1]  (xl2 aliases A0+A1 later)
    float* hbuf  = (float*)alloc(NF);
    float* o1    = (float*)alloc(NF);   // [B0]
    /* spare */    (void)   alloc(NF);  // [B1]  (xr2 aliases B0+B1 later)
    float* o2    = (float*)alloc(NF);
    int*   offs   = (int*)  alloc((size_t)(NNODES + 1) * 4);
    int*   cursor = (int*)  alloc((size_t)NNODES * 4);
    int*   deg    = (int*)  alloc((size_t)NNODES * 4);
    int*   esrc   = (int*)  alloc((size_t)EPTOT * 4);
    int*   bsum   = (int*)  alloc(64 * 4);
    int*   bbase  = (int*)  alloc(64 * 4);
    float* bnsums = (float*)alloc(384 * 4);   // bn1: 256 (sum|sq), bn2: 128 (sum|sq)
    float* ss1    = (float*)alloc(256 * 4);   // bn1 scale|shift
    float* ms2    = (float*)alloc(128 * 4);   // bn2 mu|rsqrt
    float* bn1s = bnsums;
    float* bn2s = bnsums + 256;
    float* xl2 = xl1;   // spans A0+A1 (xl1/xr1 dead after layer-1 aggregate)
    float* xr2 = o1;    // spans B0+B1 (o1 dead after bn_apply_relu)

    hipMemsetAsync(deg, 0, (size_t)NNODES * 4, stream);
    hipMemsetAsync(bnsums, 0, 384 * 4, stream);

    // CSR by destination
    count_deg<<<(EPTOT + 255) / 256, 256, 0, stream>>>(ei, deg);
    scan1<<<49, 1024, 0, stream>>>(deg, offs, bsum);
    scan2<<<1, 64, 0, stream>>>(bsum, bbase, offs);
    scan3<<<49, 1024, 0, stream>>>(offs, bbase, cursor);
    scatter_edges<<<(EPTOT + 255) / 256, 256, 0, stream>>>(ei, cursor, esrc);

    // conv1
    gemm_bias<128><<<dim3(1563, 2), 256, 0, stream>>>(x, W_l1, b_l1, xl1);
    gemm_bias<128><<<dim3(1563, 2), 256, 0, stream>>>(x, W_r1, b_r1, xr1);
    gat_aggregate<64><<<NNODES, 128, 0, stream>>>(xl1, xr1, att1, offs, esrc, o1, bias2, 0);

    // bn1 + relu
    bn_stats<128><<<128, 256, 0, stream>>>(o1, bn1s, 128);
    bn1_finalize<<<1, 128, 0, stream>>>(bn1s, gamma1, beta1, ss1);
    bn_apply_relu<<<(NNODES * 128 + 255) / 256, 256, 0, stream>>>(o1, ss1, hbuf);

    // conv2
    gemm_bias<256><<<dim3(1563, 4), 256, 0, stream>>>(hbuf, W_l2, b_l2, xl2);
    gemm_bias<256><<<dim3(1563, 4), 256, 0, stream>>>(hbuf, W_r2, b_r2, xr2);
    gat_aggregate<128><<<NNODES, 128, 0, stream>>>(xl2, xr2, att2, offs, esrc, o2, bias2, 1);

    // bn2 (cols 0..63, affine=False) + softplus (cols 64..127)
    bn_stats<64><<<128, 256, 0, stream>>>(o2, bn2s, 128);
    bn2_finalize<<<1, 64, 0, stream>>>(bn2s, ms2);
    final_out<<<(NNODES * 128 + 255) / 256, 256, 0, stream>>>(o2, ms2, out);
}

// Round 3
// 901.039 us; speedup vs baseline: 1.2757x; 1.2757x over previous
//
#include <hip/hip_runtime.h>
#include <hip/hip_bf16.h>
#include <math.h>

#define NNODES 50000
#define NEDGES 800000
#define EPTOT  (NEDGES + NNODES)   // 850000 edges incl self-loops
#define NEG_SLOPE 0.2f
#define BN_EPS 1e-5f

typedef __hip_bfloat16 bf16;

__device__ __forceinline__ float us2f(unsigned short u){
    union { unsigned int i; float f; } v; v.i = ((unsigned int)u) << 16; return v.f;
}
__device__ __forceinline__ unsigned short f2us(float f){
    return (unsigned short)(__bfloat16_as_ushort(__float2bfloat16(f)));
}

// ---------------- CSR build ----------------

__global__ void count_deg(const int* __restrict__ ei, int* __restrict__ deg){
    int e = blockIdx.x * blockDim.x + threadIdx.x;
    if (e >= EPTOT) return;
    int dst = (e < NEDGES) ? ei[NEDGES + e] : (e - NEDGES);
    atomicAdd(&deg[dst], 1);
}

__global__ void scan1(const int* __restrict__ deg, int* __restrict__ offs, int* __restrict__ bsum){
    __shared__ int s[1024];
    int t = threadIdx.x;
    int i = blockIdx.x * 1024 + t;
    int v = (i < NNODES) ? deg[i] : 0;
    s[t] = v;
    for (int o = 1; o < 1024; o <<= 1){
        __syncthreads();
        int x = (t >= o) ? s[t - o] : 0;
        __syncthreads();
        s[t] += x;
    }
    if (i < NNODES) offs[i] = s[t] - v;     // exclusive, block-local
    if (t == 1023) bsum[blockIdx.x] = s[1023];
}

__global__ void scan2(const int* __restrict__ bsum, int* __restrict__ bbase, int* __restrict__ offs){
    if (threadIdx.x == 0 && blockIdx.x == 0){
        int run = 0;
        for (int b = 0; b < 49; ++b){ bbase[b] = run; run += bsum[b]; }
        offs[NNODES] = EPTOT;
    }
}

__global__ void scan3(int* __restrict__ offs, const int* __restrict__ bbase, int* __restrict__ cursor){
    int i = blockIdx.x * 1024 + threadIdx.x;
    if (i < NNODES){
        int v = offs[i] + bbase[blockIdx.x];
        offs[i] = v;
        cursor[i] = v;
    }
}

__global__ void scatter_edges(const int* __restrict__ ei, int* __restrict__ cursor, int* __restrict__ esrc){
    int e = blockIdx.x * blockDim.x + threadIdx.x;
    if (e >= EPTOT) return;
    int s, d;
    if (e < NEDGES){ s = ei[e]; d = ei[NEDGES + e]; } else { s = d = e - NEDGES; }
    int pos = atomicAdd(&cursor[d], 1);
    esrc[pos] = s;
}

// ---------------- GEMM: out[N x DTOT] = A[N x 128] @ B[128 x DTOT] + bias (bf16 out) ----------------
// 32 rows x 64 cols per block, 256 threads, fp32 accum, LDS-staged A tile + B tile.

template<int DTOT>
__global__ __launch_bounds__(256) void gemm_bias(const float* __restrict__ A, const float* __restrict__ B,
                                                 const float* __restrict__ bias, bf16* __restrict__ out){
    __shared__ float Bs[128 * 64];   // [k][c] 32 KB
    __shared__ float As[32 * 128];   // [r][k] 16 KB
    int t  = threadIdx.x;
    int c0 = blockIdx.y * 64;
    int r0 = blockIdx.x * 32;

    for (int i = t; i < 128 * 64; i += 256){
        int k = i >> 6, c = i & 63;
        Bs[i] = B[k * DTOT + c0 + c];
    }
    for (int i = t; i < 32 * 128; i += 256){
        int r = i >> 7, k = i & 127;
        int row = r0 + r;
        As[i] = (row < NNODES) ? A[(size_t)row * 128 + k] : 0.f;
    }
    __syncthreads();

    int tx = t & 31;    // col pair index: cols 2*tx, 2*tx+1
    int ty = t >> 5;    // 0..7, rows ty + 8*j
    float acc[4][2] = {};
    const float2* Bs2 = (const float2*)Bs;
    #pragma unroll 4
    for (int k = 0; k < 128; ++k){
        float2 b = Bs2[k * 32 + tx];
        #pragma unroll
        for (int j = 0; j < 4; ++j){
            float a = As[(ty + 8 * j) * 128 + k];
            acc[j][0] += a * b.x;
            acc[j][1] += a * b.y;
        }
    }

    int c = c0 + 2 * tx;
    float bi0 = bias[c], bi1 = bias[c + 1];
    #pragma unroll
    for (int j = 0; j < 4; ++j){
        int r = r0 + ty + 8 * j;
        if (r < NNODES){
            unsigned int lo = f2us(acc[j][0] + bi0);
            unsigned int hi = f2us(acc[j][1] + bi1);
            *(unsigned int*)&out[(size_t)r * DTOT + c] = lo | (hi << 16);  // c even -> 4B aligned
        }
    }
}

// ---------------- GATv2 per-node aggregation: ONE pass, online softmax ----------------
// One block per destination node, 128 threads = 2 waves, wave = head.
// Lane owns VPT contiguous channels (one 4B/2B bf16 load). Logit reduction =
// 64-lane butterfly (wave-uniform). Branchless online-softmax rescale.

template<int C>
__global__ __launch_bounds__(128) void gat_aggregate(
    const bf16* __restrict__ xl, const bf16* __restrict__ xr,
    const float* __restrict__ att, const int* __restrict__ offs,
    const int* __restrict__ esrc, float* __restrict__ out,
    const float* __restrict__ bias2, int mean_heads)
{
    constexpr int VPT = C / 64;     // 1 (C=64) or 2 (C=128)
    constexpr int HC  = 2 * C;
    __shared__ float tmp[HC];
    int n    = blockIdx.x;
    int lane = threadIdx.x & 63;
    int head = threadIdx.x >> 6;
    size_t rowbase = (size_t)n * HC + head * C + lane * VPT;

    float xrv[VPT], av[VPT];
    #pragma unroll
    for (int v = 0; v < VPT; ++v){
        xrv[v] = us2f(((const unsigned short*)xr)[rowbase + v]);
        av[v]  = att[head * C + lane * VPT + v];
    }
    int e0 = offs[n], e1 = offs[n + 1];

    float m = -1e30f, den = 0.f, acc[VPT] = {};
    for (int p = e0; p < e1; ++p){
        int s = esrc[p];
        size_t sb = (size_t)s * HC + head * C + lane * VPT;
        float xlv[VPT];
        if (VPT == 2){
            unsigned int w = *(const unsigned int*)((const unsigned short*)xl + sb);
            xlv[0] = us2f((unsigned short)(w & 0xffff));
            xlv[1] = us2f((unsigned short)(w >> 16));
        } else {
            xlv[0] = us2f(((const unsigned short*)xl)[sb]);
        }
        float part = 0.f;
        #pragma unroll
        for (int v = 0; v < VPT; ++v){
            float u = xlv[v] + xrv[v];
            u = (u > 0.f) ? u : NEG_SLOPE * u;
            part += u * av[v];
        }
        #pragma unroll
        for (int o = 32; o > 0; o >>= 1) part += __shfl_xor(part, o, 64);
        float mnew  = fmaxf(m, part);
        float scale = __expf(m - mnew);       // 0 on first edge, 1 if max unchanged
        float ex    = __expf(part - mnew);
        den = den * scale + ex;
        #pragma unroll
        for (int v = 0; v < VPT; ++v) acc[v] = acc[v] * scale + ex * xlv[v];
        m = mnew;
    }
    float inv = 1.f / den;

    if (!mean_heads){
        #pragma unroll
        for (int v = 0; v < VPT; ++v) out[rowbase + v] = acc[v] * inv;
    } else {
        #pragma unroll
        for (int v = 0; v < VPT; ++v) tmp[head * C + lane * VPT + v] = acc[v] * inv;
        __syncthreads();
        if (head == 0){
            #pragma unroll
            for (int v = 0; v < VPT; ++v){
                int c = lane * VPT + v;
                out[(size_t)n * C + c] = 0.5f * (tmp[c] + tmp[C + c]) + bias2[c];
            }
        }
    }
}

// ---------------- BatchNorm ----------------

template<int COLS>
__global__ void bn_stats(const float* __restrict__ x, float* __restrict__ sums, int stride){
    __shared__ float ls[512];
    int t = threadIdx.x;              // 256 threads
    int col = t % COLS;
    int rg  = t / COLS;
    const int RG = 256 / COLS;
    float s = 0.f, q = 0.f;
    for (int r = blockIdx.x * RG + rg; r < NNODES; r += gridDim.x * RG){
        float v = x[(size_t)r * stride + col];
        s += v; q += v * v;
    }
    ls[t] = s; ls[256 + t] = q;
    __syncthreads();
    if (rg == 0){
        for (int g = 1; g < RG; ++g){ s += ls[g * COLS + col]; q += ls[256 + g * COLS + col]; }
        atomicAdd(&sums[col], s);
        atomicAdd(&sums[COLS + col], q);
    }
}

__global__ void bn1_finalize(const float* __restrict__ sums, const float* __restrict__ gamma,
                             const float* __restrict__ beta, float* __restrict__ ss){
    int c = threadIdx.x;              // 128
    float mu  = sums[c] / (float)NNODES;
    float var = sums[128 + c] / (float)NNODES - mu * mu;
    float sc  = gamma[c] * rsqrtf(var + BN_EPS);
    ss[c]       = sc;
    ss[128 + c] = beta[c] - mu * sc;
}

__global__ void bn_apply_relu(const float* __restrict__ o1, const float* __restrict__ ss,
                              float* __restrict__ h){
    int i = blockIdx.x * blockDim.x + threadIdx.x;
    if (i >= NNODES * 128) return;
    int c = i & 127;
    float v = o1[i] * ss[c] + ss[128 + c];
    h[i] = v > 0.f ? v : 0.f;
}

__global__ void bn2_finalize(const float* __restrict__ sums, float* __restrict__ ms){
    int c = threadIdx.x;              // 64
    float mu  = sums[c] / (float)NNODES;
    float var = sums[64 + c] / (float)NNODES - mu * mu;
    ms[c]      = mu;
    ms[64 + c] = rsqrtf(var + BN_EPS);
}

__global__ void final_out(const float* __restrict__ o2, const float* __restrict__ ms,
                          float* __restrict__ out){
    int i = blockIdx.x * blockDim.x + threadIdx.x;
    if (i >= NNODES * 128) return;
    int c = i & 127;
    float v = o2[i];
    float r;
    if (c < 64){
        r = (v - ms[c]) * ms[64 + c];           // BN, affine=False
    } else {
        r = (v > 20.f) ? v : log1pf(__expf(v)); // softplus
    }
    out[i] = r;
}

// ---------------- launch ----------------

extern "C" void kernel_launch(void* const* d_in, const int* in_sizes, int n_in,
                              void* d_out, int out_size, void* d_ws, size_t ws_size,
                              hipStream_t stream) {
    const float* x     = (const float*)d_in[0];
    const int*   ei    = (const int*)d_in[1];
    const float* W_l1  = (const float*)d_in[2];
    const float* b_l1  = (const float*)d_in[3];
    const float* W_r1  = (const float*)d_in[4];
    const float* b_r1  = (const float*)d_in[5];
    const float* att1  = (const float*)d_in[6];
    // d_in[7] = bias1: cancels through BN1 (constant per-column shift) -> unused
    const float* gamma1 = (const float*)d_in[8];
    const float* beta1  = (const float*)d_in[9];
    const float* W_l2  = (const float*)d_in[10];
    const float* b_l2  = (const float*)d_in[11];
    const float* W_r2  = (const float*)d_in[12];
    const float* b_r2  = (const float*)d_in[13];
    const float* att2  = (const float*)d_in[14];
    const float* bias2 = (const float*)d_in[15];
    float* out = (float*)d_out;

    char* w = (char*)d_ws;
    size_t off = 0;
    auto alloc = [&](size_t bytes) -> void* {
        void* p = w + off;
        off += (bytes + 255) & ~(size_t)255;
        return p;
    };
    const size_t NF  = (size_t)NNODES * 128 * 4;   // 25.6 MB fp32
    bf16*  xl1   = (bf16*) alloc(NF / 2);          // N x 128 bf16
    bf16*  xr1   = (bf16*) alloc(NF / 2);
    bf16*  xl2   = (bf16*) alloc(NF);              // N x 256 bf16
    bf16*  xr2   = (bf16*) alloc(NF);
    float* hbuf  = (float*)alloc(NF);
    float* o1    = (float*)alloc(NF);
    float* o2    = (float*)alloc(NF);
    int*   offs   = (int*)  alloc((size_t)(NNODES + 1) * 4);
    int*   cursor = (int*)  alloc((size_t)NNODES * 4);
    int*   deg    = (int*)  alloc((size_t)NNODES * 4);
    int*   esrc   = (int*)  alloc((size_t)EPTOT * 4);
    int*   bsum   = (int*)  alloc(64 * 4);
    int*   bbase  = (int*)  alloc(64 * 4);
    float* bnsums = (float*)alloc(384 * 4);   // bn1: 256 (sum|sq), bn2: 128 (sum|sq)
    float* ss1    = (float*)alloc(256 * 4);   // bn1 scale|shift
    float* ms2    = (float*)alloc(128 * 4);   // bn2 mu|rsqrt
    float* bn1s = bnsums;
    float* bn2s = bnsums + 256;

    hipMemsetAsync(deg, 0, (size_t)NNODES * 4, stream);
    hipMemsetAsync(bnsums, 0, 384 * 4, stream);

    // CSR by destination
    count_deg<<<(EPTOT + 255) / 256, 256, 0, stream>>>(ei, deg);
    scan1<<<49, 1024, 0, stream>>>(deg, offs, bsum);
    scan2<<<1, 64, 0, stream>>>(bsum, bbase, offs);
    scan3<<<49, 1024, 0, stream>>>(offs, bbase, cursor);
    scatter_edges<<<(EPTOT + 255) / 256, 256, 0, stream>>>(ei, cursor, esrc);

    // conv1
    gemm_bias<128><<<dim3(1563, 2), 256, 0, stream>>>(x, W_l1, b_l1, xl1);
    gemm_bias<128><<<dim3(1563, 2), 256, 0, stream>>>(x, W_r1, b_r1, xr1);
    gat_aggregate<64><<<NNODES, 128, 0, stream>>>(xl1, xr1, att1, offs, esrc, o1, bias2, 0);

    // bn1 + relu
    bn_stats<128><<<128, 256, 0, stream>>>(o1, bn1s, 128);
    bn1_finalize<<<1, 128, 0, stream>>>(bn1s, gamma1, beta1, ss1);
    bn_apply_relu<<<(NNODES * 128 + 255) / 256, 256, 0, stream>>>(o1, ss1, hbuf);

    // conv2
    gemm_bias<256><<<dim3(1563, 4), 256, 0, stream>>>(hbuf, W_l2, b_l2, xl2);
    gemm_bias<256><<<dim3(1563, 4), 256, 0, stream>>>(hbuf, W_r2, b_r2, xr2);
    gat_aggregate<128><<<NNODES, 128, 0, stream>>>(xl2, xr2, att2, offs, esrc, o2, bias2, 1);

    // bn2 (cols 0..63, affine=False) + softplus (cols 64..127)
    bn_stats<64><<<128, 256, 0, stream>>>(o2, bn2s, 128);
    bn2_finalize<<<1, 64, 0, stream>>>(bn2s, ms2);
    final_out<<<(NNODES * 128 + 255) / 256, 256, 0, stream>>>(o2, ms2, out);
}

// Round 4
// 698.771 us; speedup vs baseline: 1.6449x; 1.2895x over previous
//
#include <hip/hip_runtime.h>
#include <hip/hip_bf16.h>
#include <math.h>

#define NNODES 50000
#define NEDGES 800000
#define EPTOT  (NEDGES + NNODES)   // 850000 edges incl self-loops
#define NEG_SLOPE 0.2f
#define BN_EPS 1e-5f
#define LOG2E 1.44269504088896f

typedef __hip_bfloat16 bf16;
typedef __attribute__((ext_vector_type(8))) short short8;
typedef __attribute__((ext_vector_type(4))) float f32x4;

__device__ __forceinline__ float us2f(unsigned short u){
    union { unsigned int i; float f; } v; v.i = ((unsigned int)u) << 16; return v.f;
}
__device__ __forceinline__ unsigned short f2us(float f){
    return (unsigned short)(__bfloat16_as_ushort(__float2bfloat16(f)));
}

// ---------------- CSR build ----------------

__global__ void count_deg(const int* __restrict__ ei, int* __restrict__ deg){
    int e = blockIdx.x * blockDim.x + threadIdx.x;
    if (e >= EPTOT) return;
    int dst = (e < NEDGES) ? ei[NEDGES + e] : (e - NEDGES);
    atomicAdd(&deg[dst], 1);
}

__global__ void scan1(const int* __restrict__ deg, int* __restrict__ offs, int* __restrict__ bsum){
    __shared__ int s[1024];
    int t = threadIdx.x;
    int i = blockIdx.x * 1024 + t;
    int v = (i < NNODES) ? deg[i] : 0;
    s[t] = v;
    for (int o = 1; o < 1024; o <<= 1){
        __syncthreads();
        int x = (t >= o) ? s[t - o] : 0;
        __syncthreads();
        s[t] += x;
    }
    if (i < NNODES) offs[i] = s[t] - v;     // exclusive, block-local
    if (t == 1023) bsum[blockIdx.x] = s[1023];
}

__global__ void scan2(const int* __restrict__ bsum, int* __restrict__ bbase, int* __restrict__ offs){
    if (threadIdx.x == 0 && blockIdx.x == 0){
        int run = 0;
        for (int b = 0; b < 49; ++b){ bbase[b] = run; run += bsum[b]; }
        offs[NNODES] = EPTOT;
    }
}

__global__ void scan3(int* __restrict__ offs, const int* __restrict__ bbase, int* __restrict__ cursor){
    int i = blockIdx.x * 1024 + threadIdx.x;
    if (i < NNODES){
        int v = offs[i] + bbase[blockIdx.x];
        offs[i] = v;
        cursor[i] = v;
    }
}

__global__ void scatter_edges(const int* __restrict__ ei, int* __restrict__ cursor, int* __restrict__ esrc){
    int e = blockIdx.x * blockDim.x + threadIdx.x;
    if (e >= EPTOT) return;
    int s, d;
    if (e < NEDGES){ s = ei[e]; d = ei[NEDGES + e]; } else { s = d = e - NEDGES; }
    int pos = atomicAdd(&cursor[d], 1);
    esrc[pos] = s;
}

// ---------------- dtype prep ----------------

__global__ void to_bf16_pack(const float* __restrict__ in, unsigned int* __restrict__ out, int n2){
    int i = blockIdx.x * blockDim.x + threadIdx.x;
    if (i >= n2) return;
    float2 v = ((const float2*)in)[i];
    out[i] = (unsigned int)f2us(v.x) | ((unsigned int)f2us(v.y) << 16);
}

// W[128][DTOT] fp32 (l and r) -> WT[2*DTOT][128] bf16 (transposed, l rows then r rows)
// biascat[2*DTOT] fp32 = [b_l | b_r]
template<int DTOT>
__global__ void prep_w(const float* __restrict__ Wl, const float* __restrict__ Wr,
                       const float* __restrict__ bl, const float* __restrict__ br,
                       bf16* __restrict__ WT, float* __restrict__ biascat){
    int i = blockIdx.x * 256 + threadIdx.x;     // over 2*DTOT*128
    if (i >= 2 * DTOT * 128) return;
    int r = i >> 7;           // output row = weight column (0..2*DTOT)
    int k = i & 127;
    const float* W = (r < DTOT) ? Wl : Wr;
    int c = (r < DTOT) ? r : r - DTOT;
    WT[i] = __float2bfloat16(W[k * DTOT + c]);
    if (k == 0) biascat[r] = (r < DTOT) ? bl[c] : br[c];
}

// ---------------- MFMA GEMM: [M x 128] @ [128 x 2*DTOT] -> xl,xr [M x DTOT] bf16 ----------------
// No LDS. 256 threads = 4 waves; wave = 64 rows x 64 cols via 4x4 16x16x32 frags.
// A frag: lane holds A[m = lane&15][k = (lane>>4)*8 + j]; B frag symmetric on columns.
// C/D: col = lane&15, row = (lane>>4)*4 + reg  [m89-verified].

template<int DTOT>
__global__ __launch_bounds__(256) void mfma_gemm(
    const bf16* __restrict__ A, const bf16* __restrict__ WT,
    const float* __restrict__ biascat,
    bf16* __restrict__ xl, bf16* __restrict__ xr)
{
    int wave = threadIdx.x >> 6;
    int lane = threadIdx.x & 63;
    int quad = lane >> 4;
    int l16  = lane & 15;
    int m0 = blockIdx.x * 256 + wave * 64;
    int n0 = blockIdx.y * 64;

    f32x4 acc[4][4] = {};
    const short* Ap = (const short*)A;
    const short* Bp = (const short*)WT;

    #pragma unroll
    for (int k0 = 0; k0 < 128; k0 += 32){
        short8 af[4], bfr[4];
        #pragma unroll
        for (int mt = 0; mt < 4; ++mt){
            int m = m0 + mt * 16 + l16;
            m = (m < NNODES) ? m : (NNODES - 1);    // clamp; garbage rows never stored
            af[mt] = *(const short8*)(Ap + (size_t)m * 128 + k0 + quad * 8);
        }
        #pragma unroll
        for (int nt = 0; nt < 4; ++nt){
            int n = n0 + nt * 16 + l16;
            bfr[nt] = *(const short8*)(Bp + (size_t)n * 128 + k0 + quad * 8);
        }
        #pragma unroll
        for (int mt = 0; mt < 4; ++mt)
            #pragma unroll
            for (int nt = 0; nt < 4; ++nt)
                acc[mt][nt] = __builtin_amdgcn_mfma_f32_16x16x32_bf16(af[mt], bfr[nt], acc[mt][nt], 0, 0, 0);
    }

    #pragma unroll
    for (int nt = 0; nt < 4; ++nt){
        int n = n0 + nt * 16 + l16;
        float bi = biascat[n];
        bf16* outp = (n < DTOT) ? xl : xr;
        int c = (n < DTOT) ? n : n - DTOT;
        #pragma unroll
        for (int mt = 0; mt < 4; ++mt)
            #pragma unroll
            for (int r = 0; r < 4; ++r){
                int m = m0 + mt * 16 + quad * 4 + r;
                if (m < NNODES)
                    outp[(size_t)m * DTOT + c] = __float2bfloat16(acc[mt][nt][r] + bi);
            }
    }
}

// ---------------- GATv2 per-node aggregation: ONE pass, online softmax ----------------
// Block = node, 128 threads = 2 waves, wave = head. Lane owns VPT contiguous channels.
// att pre-scaled by log2(e) so softmax runs in exp2 domain. Wave-uniform skip of the
// accumulator rescale when the running max is unchanged.

template<int C>
__global__ __launch_bounds__(128) void gat_aggregate(
    const bf16* __restrict__ xl, const bf16* __restrict__ xr,
    const float* __restrict__ att, const int* __restrict__ offs,
    const int* __restrict__ esrc, float* __restrict__ out,
    const float* __restrict__ bias2, int mean_heads)
{
    constexpr int VPT = C / 64;     // 1 (C=64) or 2 (C=128)
    constexpr int HC  = 2 * C;
    __shared__ float tmp[HC];
    int n    = blockIdx.x;
    int lane = threadIdx.x & 63;
    int head = threadIdx.x >> 6;
    size_t rowbase = (size_t)n * HC + head * C + lane * VPT;

    float xrv[VPT], av[VPT];
    #pragma unroll
    for (int v = 0; v < VPT; ++v){
        xrv[v] = us2f(((const unsigned short*)xr)[rowbase + v]);
        av[v]  = att[head * C + lane * VPT + v] * LOG2E;
    }
    int e0 = offs[n], e1 = offs[n + 1];

    float m = -1e30f, den = 0.f, acc[VPT] = {};
    for (int p = e0; p < e1; ++p){
        int s = esrc[p];
        size_t sb = (size_t)s * HC + head * C + lane * VPT;
        float xlv[VPT];
        if (VPT == 2){
            unsigned int w = *(const unsigned int*)((const unsigned short*)xl + sb);
            xlv[0] = us2f((unsigned short)(w & 0xffff));
            xlv[1] = us2f((unsigned short)(w >> 16));
        } else {
            xlv[0] = us2f(((const unsigned short*)xl)[sb]);
        }
        float part = 0.f;
        #pragma unroll
        for (int v = 0; v < VPT; ++v){
            float u = xlv[v] + xrv[v];
            part += fmaxf(u, NEG_SLOPE * u) * av[v];   // leaky_relu = max(u, 0.2u)
        }
        #pragma unroll
        for (int o = 32; o > 0; o >>= 1) part += __shfl_xor(part, o, 64);
        if (part > m){                 // wave-uniform: rescale path (rare after warmup)
            float scale = exp2f(m - part);             // 0 on first edge
            den = den * scale + 1.f;                   // ex = exp2(0) = 1
            #pragma unroll
            for (int v = 0; v < VPT; ++v) acc[v] = acc[v] * scale + xlv[v];
            m = part;
        } else {                       // fast path: max unchanged
            float ex = exp2f(part - m);
            den += ex;
            #pragma unroll
            for (int v = 0; v < VPT; ++v) acc[v] += ex * xlv[v];
        }
    }
    float inv = 1.f / den;

    if (!mean_heads){
        #pragma unroll
        for (int v = 0; v < VPT; ++v) out[rowbase + v] = acc[v] * inv;
    } else {
        #pragma unroll
        for (int v = 0; v < VPT; ++v) tmp[head * C + lane * VPT + v] = acc[v] * inv;
        __syncthreads();
        if (head == 0){
            #pragma unroll
            for (int v = 0; v < VPT; ++v){
                int c = lane * VPT + v;
                out[(size_t)n * C + c] = 0.5f * (tmp[c] + tmp[C + c]) + bias2[c];
            }
        }
    }
}

// ---------------- BatchNorm ----------------

template<int COLS>
__global__ void bn_stats(const float* __restrict__ x, float* __restrict__ sums, int stride){
    __shared__ float ls[512];
    int t = threadIdx.x;              // 256 threads
    int col = t % COLS;
    int rg  = t / COLS;
    const int RG = 256 / COLS;
    float s = 0.f, q = 0.f;
    for (int r = blockIdx.x * RG + rg; r < NNODES; r += gridDim.x * RG){
        float v = x[(size_t)r * stride + col];
        s += v; q += v * v;
    }
    ls[t] = s; ls[256 + t] = q;
    __syncthreads();
    if (rg == 0){
        for (int g = 1; g < RG; ++g){ s += ls[g * COLS + col]; q += ls[256 + g * COLS + col]; }
        atomicAdd(&sums[col], s);
        atomicAdd(&sums[COLS + col], q);
    }
}

__global__ void bn1_finalize(const float* __restrict__ sums, const float* __restrict__ gamma,
                             const float* __restrict__ beta, float* __restrict__ ss){
    int c = threadIdx.x;              // 128
    float mu  = sums[c] / (float)NNODES;
    float var = sums[128 + c] / (float)NNODES - mu * mu;
    float sc  = gamma[c] * rsqrtf(var + BN_EPS);
    ss[c]       = sc;
    ss[128 + c] = beta[c] - mu * sc;
}

__global__ void bn_apply_relu(const float* __restrict__ o1, const float* __restrict__ ss,
                              bf16* __restrict__ h){
    int i = blockIdx.x * blockDim.x + threadIdx.x;
    if (i >= NNODES * 64) return;     // 2 elems per thread
    float v0 = o1[2 * i]     * ss[(2 * i) & 127]     + ss[128 + ((2 * i) & 127)];
    float v1 = o1[2 * i + 1] * ss[(2 * i + 1) & 127] + ss[128 + ((2 * i + 1) & 127)];
    unsigned int lo = f2us(v0 > 0.f ? v0 : 0.f);
    unsigned int hi = f2us(v1 > 0.f ? v1 : 0.f);
    ((unsigned int*)h)[i] = lo | (hi << 16);
}

__global__ void bn2_finalize(const float* __restrict__ sums, float* __restrict__ ms){
    int c = threadIdx.x;              // 64
    float mu  = sums[c] / (float)NNODES;
    float var = sums[64 + c] / (float)NNODES - mu * mu;
    ms[c]      = mu;
    ms[64 + c] = rsqrtf(var + BN_EPS);
}

__global__ void final_out(const float* __restrict__ o2, const float* __restrict__ ms,
                          float* __restrict__ out){
    int i = blockIdx.x * blockDim.x + threadIdx.x;
    if (i >= NNODES * 128) return;
    int c = i & 127;
    float v = o2[i];
    float r;
    if (c < 64){
        r = (v - ms[c]) * ms[64 + c];           // BN, affine=False
    } else {
        r = (v > 20.f) ? v : log1pf(__expf(v)); // softplus
    }
    out[i] = r;
}

// ---------------- launch ----------------

extern "C" void kernel_launch(void* const* d_in, const int* in_sizes, int n_in,
                              void* d_out, int out_size, void* d_ws, size_t ws_size,
                              hipStream_t stream) {
    const float* x     = (const float*)d_in[0];
    const int*   ei    = (const int*)d_in[1];
    const float* W_l1  = (const float*)d_in[2];
    const float* b_l1  = (const float*)d_in[3];
    const float* W_r1  = (const float*)d_in[4];
    const float* b_r1  = (const float*)d_in[5];
    const float* att1  = (const float*)d_in[6];
    // d_in[7] = bias1: cancels through BN1 (constant per-column shift) -> unused
    const float* gamma1 = (const float*)d_in[8];
    const float* beta1  = (const float*)d_in[9];
    const float* W_l2  = (const float*)d_in[10];
    const float* b_l2  = (const float*)d_in[11];
    const float* W_r2  = (const float*)d_in[12];
    const float* b_r2  = (const float*)d_in[13];
    const float* att2  = (const float*)d_in[14];
    const float* bias2 = (const float*)d_in[15];
    float* out = (float*)d_out;

    char* w = (char*)d_ws;
    size_t off = 0;
    auto alloc = [&](size_t bytes) -> void* {
        void* p = w + off;
        off += (bytes + 255) & ~(size_t)255;
        return p;
    };
    const size_t NF  = (size_t)NNODES * 128 * 4;   // 25.6 MB fp32
    bf16*  xb    = (bf16*) alloc(NF / 2);          // x in bf16 [N][128]
    bf16*  xl1   = (bf16*) alloc(NF / 2);          // N x 128 bf16
    bf16*  xr1   = (bf16*) alloc(NF / 2);
    bf16*  xl2   = (bf16*) alloc(NF);              // N x 256 bf16
    bf16*  xr2   = (bf16*) alloc(NF);
    bf16*  hbuf  = (bf16*) alloc(NF / 2);          // N x 128 bf16
    float* o1    = (float*)alloc(NF);
    float* o2    = (float*)alloc(NF);
    bf16*  WT1   = (bf16*) alloc(256 * 128 * 2);
    bf16*  WT2   = (bf16*) alloc(512 * 128 * 2);
    float* bc1   = (float*)alloc(256 * 4);
    float* bc2   = (float*)alloc(512 * 4);
    int*   offs   = (int*)  alloc((size_t)(NNODES + 1) * 4);
    int*   cursor = (int*)  alloc((size_t)NNODES * 4);
    int*   deg    = (int*)  alloc((size_t)NNODES * 4);
    int*   esrc   = (int*)  alloc((size_t)EPTOT * 4);
    int*   bsum   = (int*)  alloc(64 * 4);
    int*   bbase  = (int*)  alloc(64 * 4);
    float* bnsums = (float*)alloc(384 * 4);   // bn1: 256 (sum|sq), bn2: 128 (sum|sq)
    float* ss1    = (float*)alloc(256 * 4);   // bn1 scale|shift
    float* ms2    = (float*)alloc(128 * 4);   // bn2 mu|rsqrt
    float* bn1s = bnsums;
    float* bn2s = bnsums + 256;

    hipMemsetAsync(deg, 0, (size_t)NNODES * 4, stream);
    hipMemsetAsync(bnsums, 0, 384 * 4, stream);

    // CSR by destination
    count_deg<<<(EPTOT + 255) / 256, 256, 0, stream>>>(ei, deg);
    scan1<<<49, 1024, 0, stream>>>(deg, offs, bsum);
    scan2<<<1, 64, 0, stream>>>(bsum, bbase, offs);
    scan3<<<49, 1024, 0, stream>>>(offs, bbase, cursor);
    scatter_edges<<<(EPTOT + 255) / 256, 256, 0, stream>>>(ei, cursor, esrc);

    // dtype prep
    to_bf16_pack<<<(NNODES * 64 + 255) / 256, 256, 0, stream>>>(x, (unsigned int*)xb, NNODES * 64);
    prep_w<128><<<128, 256, 0, stream>>>(W_l1, W_r1, b_l1, b_r1, WT1, bc1);
    prep_w<256><<<256, 256, 0, stream>>>(W_l2, W_r2, b_l2, b_r2, WT2, bc2);

    // conv1: one fused GEMM (l|r), MFMA
    mfma_gemm<128><<<dim3(196, 4), 256, 0, stream>>>(xb, WT1, bc1, xl1, xr1);
    gat_aggregate<64><<<NNODES, 128, 0, stream>>>(xl1, xr1, att1, offs, esrc, o1, bias2, 0);

    // bn1 + relu (-> bf16 hbuf, GEMM2 input)
    bn_stats<128><<<128, 256, 0, stream>>>(o1, bn1s, 128);
    bn1_finalize<<<1, 128, 0, stream>>>(bn1s, gamma1, beta1, ss1);
    bn_apply_relu<<<(NNODES * 64 + 255) / 256, 256, 0, stream>>>(o1, ss1, hbuf);

    // conv2
    mfma_gemm<256><<<dim3(196, 8), 256, 0, stream>>>(hbuf, WT2, bc2, xl2, xr2);
    gat_aggregate<128><<<NNODES, 128, 0, stream>>>(xl2, xr2, att2, offs, esrc, o2, bias2, 1);

    // bn2 (cols 0..63, affine=False) + softplus (cols 64..127)
    bn_stats<64><<<128, 256, 0, stream>>>(o2, bn2s, 128);
    bn2_finalize<<<1, 64, 0, stream>>>(bn2s, ms2);
    final_out<<<(NNODES * 128 + 255) / 256, 256, 0, stream>>>(o2, ms2, out);
}

// Round 5
// 531.350 us; speedup vs baseline: 2.1632x; 1.3151x over previous
//
#include <hip/hip_runtime.h>
#include <hip/hip_bf16.h>
#include <math.h>

#define NNODES 50000
#define NEDGES 800000
#define EPTOT  (NEDGES + NNODES)   // 850000 edges incl self-loops
#define NEG_SLOPE 0.2f
#define BN_EPS 1e-5f
#define LOG2E 1.44269504088896f

typedef __hip_bfloat16 bf16;
typedef __attribute__((ext_vector_type(8))) short short8;
typedef __attribute__((ext_vector_type(4))) float f32x4;

__device__ __forceinline__ float us2f(unsigned short u){
    union { unsigned int i; float f; } v; v.i = ((unsigned int)u) << 16; return v.f;
}
__device__ __forceinline__ unsigned short f2us(float f){
    return (unsigned short)(__bfloat16_as_ushort(__float2bfloat16(f)));
}

// ---------------- CSR build ----------------

__global__ void count_deg(const int* __restrict__ ei, int* __restrict__ deg){
    int e = blockIdx.x * blockDim.x + threadIdx.x;
    if (e >= EPTOT) return;
    int dst = (e < NEDGES) ? ei[NEDGES + e] : (e - NEDGES);
    atomicAdd(&deg[dst], 1);
}

__global__ void scan1(const int* __restrict__ deg, int* __restrict__ offs, int* __restrict__ bsum){
    __shared__ int s[1024];
    int t = threadIdx.x;
    int i = blockIdx.x * 1024 + t;
    int v = (i < NNODES) ? deg[i] : 0;
    s[t] = v;
    for (int o = 1; o < 1024; o <<= 1){
        __syncthreads();
        int x = (t >= o) ? s[t - o] : 0;
        __syncthreads();
        s[t] += x;
    }
    if (i < NNODES) offs[i] = s[t] - v;     // exclusive, block-local
    if (t == 1023) bsum[blockIdx.x] = s[1023];
}

__global__ void scan2(const int* __restrict__ bsum, int* __restrict__ bbase, int* __restrict__ offs){
    if (threadIdx.x == 0 && blockIdx.x == 0){
        int run = 0;
        for (int b = 0; b < 49; ++b){ bbase[b] = run; run += bsum[b]; }
        offs[NNODES] = EPTOT;
    }
}

__global__ void scan3(int* __restrict__ offs, const int* __restrict__ bbase, int* __restrict__ cursor){
    int i = blockIdx.x * 1024 + threadIdx.x;
    if (i < NNODES){
        int v = offs[i] + bbase[blockIdx.x];
        offs[i] = v;
        cursor[i] = v;
    }
}

__global__ void scatter_edges(const int* __restrict__ ei, int* __restrict__ cursor, int* __restrict__ esrc){
    int e = blockIdx.x * blockDim.x + threadIdx.x;
    if (e >= EPTOT) return;
    int s, d;
    if (e < NEDGES){ s = ei[e]; d = ei[NEDGES + e]; } else { s = d = e - NEDGES; }
    int pos = atomicAdd(&cursor[d], 1);
    esrc[pos] = s;
}

// ---------------- dtype prep ----------------

__global__ void to_bf16_pack(const float* __restrict__ in, unsigned int* __restrict__ out, int n2){
    int i = blockIdx.x * blockDim.x + threadIdx.x;
    if (i >= n2) return;
    float2 v = ((const float2*)in)[i];
    out[i] = (unsigned int)f2us(v.x) | ((unsigned int)f2us(v.y) << 16);
}

// W[128][DTOT] fp32 (l and r) -> WT[2*DTOT][128] bf16 (transposed, l rows then r rows)
template<int DTOT>
__global__ void prep_w(const float* __restrict__ Wl, const float* __restrict__ Wr,
                       const float* __restrict__ bl, const float* __restrict__ br,
                       bf16* __restrict__ WT, float* __restrict__ biascat){
    int i = blockIdx.x * 256 + threadIdx.x;     // over 2*DTOT*128
    if (i >= 2 * DTOT * 128) return;
    int r = i >> 7;           // output row = weight column (0..2*DTOT)
    int k = i & 127;
    const float* W = (r < DTOT) ? Wl : Wr;
    int c = (r < DTOT) ? r : r - DTOT;
    WT[i] = __float2bfloat16(W[k * DTOT + c]);
    if (k == 0) biascat[r] = (r < DTOT) ? bl[c] : br[c];
}

// ---------------- MFMA GEMM: [M x 128] @ [128 x 2*DTOT] -> xl,xr [M x DTOT] bf16 ----------------
// No LDS. 256 threads = 4 waves; wave = 64 rows x 64 cols via 4x4 16x16x32 frags.
// C/D: col = lane&15, row = (lane>>4)*4 + reg  [m89-verified].

template<int DTOT>
__global__ __launch_bounds__(256) void mfma_gemm(
    const bf16* __restrict__ A, const bf16* __restrict__ WT,
    const float* __restrict__ biascat,
    bf16* __restrict__ xl, bf16* __restrict__ xr)
{
    int wave = threadIdx.x >> 6;
    int lane = threadIdx.x & 63;
    int quad = lane >> 4;
    int l16  = lane & 15;
    int m0 = blockIdx.x * 256 + wave * 64;
    int n0 = blockIdx.y * 64;

    f32x4 acc[4][4] = {};
    const short* Ap = (const short*)A;
    const short* Bp = (const short*)WT;

    #pragma unroll
    for (int k0 = 0; k0 < 128; k0 += 32){
        short8 af[4], bfr[4];
        #pragma unroll
        for (int mt = 0; mt < 4; ++mt){
            int m = m0 + mt * 16 + l16;
            m = (m < NNODES) ? m : (NNODES - 1);    // clamp; garbage rows never stored
            af[mt] = *(const short8*)(Ap + (size_t)m * 128 + k0 + quad * 8);
        }
        #pragma unroll
        for (int nt = 0; nt < 4; ++nt){
            int n = n0 + nt * 16 + l16;
            bfr[nt] = *(const short8*)(Bp + (size_t)n * 128 + k0 + quad * 8);
        }
        #pragma unroll
        for (int mt = 0; mt < 4; ++mt)
            #pragma unroll
            for (int nt = 0; nt < 4; ++nt)
                acc[mt][nt] = __builtin_amdgcn_mfma_f32_16x16x32_bf16(af[mt], bfr[nt], acc[mt][nt], 0, 0, 0);
    }

    #pragma unroll
    for (int nt = 0; nt < 4; ++nt){
        int n = n0 + nt * 16 + l16;
        float bi = biascat[n];
        bf16* outp = (n < DTOT) ? xl : xr;
        int c = (n < DTOT) ? n : n - DTOT;
        #pragma unroll
        for (int mt = 0; mt < 4; ++mt)
            #pragma unroll
            for (int r = 0; r < 4; ++r){
                int m = m0 + mt * 16 + quad * 4 + r;
                if (m < NNODES)
                    outp[(size_t)m * DTOT + c] = __float2bfloat16(acc[mt][nt][r] + bi);
            }
    }
}

// ---------------- GATv2 per-node aggregation: multi-edge waves, no max-tracking ----------------
// Block = node, 128 threads = 2 waves, wave = head.
// Lane layout: group g = lane/G handles edge slot g; chunk cl = lane%G owns 8 bf16
// channels (16B load). E = 64/G edges per iteration; butterfly = log2(G) shfls shared
// by E edges. Logits bounded (|l| < ~4) -> exp2 without max subtraction is safe in
// fp32; removes the loop-carried rescale chain entirely. Tail masked via part-1e30.

template<int C>
__global__ __launch_bounds__(128) void gat_aggregate(
    const bf16* __restrict__ xl, const bf16* __restrict__ xr,
    const float* __restrict__ att, const int* __restrict__ offs,
    const int* __restrict__ esrc, float* __restrict__ out,
    const float* __restrict__ bias2, int mean_heads)
{
    constexpr int VPT = 8;
    constexpr int G   = C / VPT;      // lanes per edge group: 8 (C=64) / 16 (C=128)
    constexpr int E   = 64 / G;       // edges per iter: 8 / 4
    constexpr int HC  = 2 * C;
    __shared__ float tmp[HC];
    int n    = blockIdx.x;
    int lane = threadIdx.x & 63;
    int head = threadIdx.x >> 6;
    int g    = lane / G;              // edge slot in iter
    int cl   = lane % G;              // channel chunk
    size_t rowoff = (size_t)head * C + cl * VPT;   // bf16-element offset in a row

    const unsigned short* xlp = (const unsigned short*)xl;

    float xrv[VPT], av[VPT];
    {
        short8 xw = *(const short8*)((const unsigned short*)xr + (size_t)n * HC + rowoff);
        #pragma unroll
        for (int v = 0; v < VPT; ++v){
            xrv[v] = us2f((unsigned short)xw[v]);
            av[v]  = att[head * C + cl * VPT + v] * LOG2E;
        }
    }
    int e0 = offs[n], e1 = offs[n + 1];

    float den = 0.f, acc[VPT] = {};
    for (int p0 = e0; p0 < e1; p0 += E){
        int p = p0 + g;
        float maskadd = (p < e1) ? 0.f : -1e30f;     // group-uniform
        int s = esrc[(p < e1) ? p : (e1 - 1)];
        short8 xw = *(const short8*)(xlp + (size_t)s * HC + rowoff);
        float xlv[VPT], part = 0.f;
        #pragma unroll
        for (int v = 0; v < VPT; ++v){
            xlv[v] = us2f((unsigned short)xw[v]);
            float u = xlv[v] + xrv[v];
            part += fmaxf(u, NEG_SLOPE * u) * av[v];   // leaky_relu(u) * att
        }
        #pragma unroll
        for (int mask = G / 2; mask >= 1; mask >>= 1)
            part += __shfl_xor(part, mask, 64);        // within-group reduce
        float ex = exp2f(part + maskadd);              // 0 for tail slots
        den += ex;
        #pragma unroll
        for (int v = 0; v < VPT; ++v) acc[v] += ex * xlv[v];
    }

    // merge the E group-partials (once per node)
    #pragma unroll
    for (int mask = G; mask < 64; mask <<= 1){
        den += __shfl_xor(den, mask, 64);
        #pragma unroll
        for (int v = 0; v < VPT; ++v) acc[v] += __shfl_xor(acc[v], mask, 64);
    }
    float inv = 1.f / den;

    if (!mean_heads){
        if (g == 0){
            #pragma unroll
            for (int v = 0; v < VPT; ++v)
                out[(size_t)n * HC + rowoff + v] = acc[v] * inv;
        }
    } else {
        if (g == 0){
            #pragma unroll
            for (int v = 0; v < VPT; ++v) tmp[head * C + cl * VPT + v] = acc[v] * inv;
        }
        __syncthreads();
        if (head == 0 && g == 0){
            #pragma unroll
            for (int v = 0; v < VPT; ++v){
                int c = cl * VPT + v;
                out[(size_t)n * C + c] = 0.5f * (tmp[c] + tmp[C + c]) + bias2[c];
            }
        }
    }
}

// ---------------- BatchNorm ----------------

template<int COLS>
__global__ void bn_stats(const float* __restrict__ x, float* __restrict__ sums, int stride){
    __shared__ float ls[512];
    int t = threadIdx.x;              // 256 threads
    int col = t % COLS;
    int rg  = t / COLS;
    const int RG = 256 / COLS;
    float s = 0.f, q = 0.f;
    for (int r = blockIdx.x * RG + rg; r < NNODES; r += gridDim.x * RG){
        float v = x[(size_t)r * stride + col];
        s += v; q += v * v;
    }
    ls[t] = s; ls[256 + t] = q;
    __syncthreads();
    if (rg == 0){
        for (int g = 1; g < RG; ++g){ s += ls[g * COLS + col]; q += ls[256 + g * COLS + col]; }
        atomicAdd(&sums[col], s);
        atomicAdd(&sums[COLS + col], q);
    }
}

__global__ void bn1_finalize(const float* __restrict__ sums, const float* __restrict__ gamma,
                             const float* __restrict__ beta, float* __restrict__ ss){
    int c = threadIdx.x;              // 128
    float mu  = sums[c] / (float)NNODES;
    float var = sums[128 + c] / (float)NNODES - mu * mu;
    float sc  = gamma[c] * rsqrtf(var + BN_EPS);
    ss[c]       = sc;
    ss[128 + c] = beta[c] - mu * sc;
}

__global__ void bn_apply_relu(const float* __restrict__ o1, const float* __restrict__ ss,
                              bf16* __restrict__ h){
    int i = blockIdx.x * blockDim.x + threadIdx.x;
    if (i >= NNODES * 64) return;     // 2 elems per thread
    float v0 = o1[2 * i]     * ss[(2 * i) & 127]     + ss[128 + ((2 * i) & 127)];
    float v1 = o1[2 * i + 1] * ss[(2 * i + 1) & 127] + ss[128 + ((2 * i + 1) & 127)];
    unsigned int lo = f2us(v0 > 0.f ? v0 : 0.f);
    unsigned int hi = f2us(v1 > 0.f ? v1 : 0.f);
    ((unsigned int*)h)[i] = lo | (hi << 16);
}

__global__ void bn2_finalize(const float* __restrict__ sums, float* __restrict__ ms){
    int c = threadIdx.x;              // 64
    float mu  = sums[c] / (float)NNODES;
    float var = sums[64 + c] / (float)NNODES - mu * mu;
    ms[c]      = mu;
    ms[64 + c] = rsqrtf(var + BN_EPS);
}

__global__ void final_out(const float* __restrict__ o2, const float* __restrict__ ms,
                          float* __restrict__ out){
    int i = blockIdx.x * blockDim.x + threadIdx.x;
    if (i >= NNODES * 128) return;
    int c = i & 127;
    float v = o2[i];
    float r;
    if (c < 64){
        r = (v - ms[c]) * ms[64 + c];           // BN, affine=False
    } else {
        r = (v > 20.f) ? v : log1pf(__expf(v)); // softplus
    }
    out[i] = r;
}

// ---------------- launch ----------------

extern "C" void kernel_launch(void* const* d_in, const int* in_sizes, int n_in,
                              void* d_out, int out_size, void* d_ws, size_t ws_size,
                              hipStream_t stream) {
    const float* x     = (const float*)d_in[0];
    const int*   ei    = (const int*)d_in[1];
    const float* W_l1  = (const float*)d_in[2];
    const float* b_l1  = (const float*)d_in[3];
    const float* W_r1  = (const float*)d_in[4];
    const float* b_r1  = (const float*)d_in[5];
    const float* att1  = (const float*)d_in[6];
    // d_in[7] = bias1: cancels through BN1 (constant per-column shift) -> unused
    const float* gamma1 = (const float*)d_in[8];
    const float* beta1  = (const float*)d_in[9];
    const float* W_l2  = (const float*)d_in[10];
    const float* b_l2  = (const float*)d_in[11];
    const float* W_r2  = (const float*)d_in[12];
    const float* b_r2  = (const float*)d_in[13];
    const float* att2  = (const float*)d_in[14];
    const float* bias2 = (const float*)d_in[15];
    float* out = (float*)d_out;

    char* w = (char*)d_ws;
    size_t off = 0;
    auto alloc = [&](size_t bytes) -> void* {
        void* p = w + off;
        off += (bytes + 255) & ~(size_t)255;
        return p;
    };
    const size_t NF  = (size_t)NNODES * 128 * 4;   // 25.6 MB fp32
    bf16*  xb    = (bf16*) alloc(NF / 2);          // x in bf16 [N][128]
    bf16*  xl1   = (bf16*) alloc(NF / 2);          // N x 128 bf16
    bf16*  xr1   = (bf16*) alloc(NF / 2);
    bf16*  xl2   = (bf16*) alloc(NF);              // N x 256 bf16
    bf16*  xr2   = (bf16*) alloc(NF);
    bf16*  hbuf  = (bf16*) alloc(NF / 2);          // N x 128 bf16
    float* o1    = (float*)alloc(NF);
    float* o2    = (float*)alloc(NF);
    bf16*  WT1   = (bf16*) alloc(256 * 128 * 2);
    bf16*  WT2   = (bf16*) alloc(512 * 128 * 2);
    float* bc1   = (float*)alloc(256 * 4);
    float* bc2   = (float*)alloc(512 * 4);
    int*   offs   = (int*)  alloc((size_t)(NNODES + 1) * 4);
    int*   cursor = (int*)  alloc((size_t)NNODES * 4);
    int*   deg    = (int*)  alloc((size_t)NNODES * 4);
    int*   esrc   = (int*)  alloc((size_t)EPTOT * 4);
    int*   bsum   = (int*)  alloc(64 * 4);
    int*   bbase  = (int*)  alloc(64 * 4);
    float* bnsums = (float*)alloc(384 * 4);   // bn1: 256 (sum|sq), bn2: 128 (sum|sq)
    float* ss1    = (float*)alloc(256 * 4);   // bn1 scale|shift
    float* ms2    = (float*)alloc(128 * 4);   // bn2 mu|rsqrt
    float* bn1s = bnsums;
    float* bn2s = bnsums + 256;

    hipMemsetAsync(deg, 0, (size_t)NNODES * 4, stream);
    hipMemsetAsync(bnsums, 0, 384 * 4, stream);

    // CSR by destination
    count_deg<<<(EPTOT + 255) / 256, 256, 0, stream>>>(ei, deg);
    scan1<<<49, 1024, 0, stream>>>(deg, offs, bsum);
    scan2<<<1, 64, 0, stream>>>(bsum, bbase, offs);
    scan3<<<49, 1024, 0, stream>>>(offs, bbase, cursor);
    scatter_edges<<<(EPTOT + 255) / 256, 256, 0, stream>>>(ei, cursor, esrc);

    // dtype prep
    to_bf16_pack<<<(NNODES * 64 + 255) / 256, 256, 0, stream>>>(x, (unsigned int*)xb, NNODES * 64);
    prep_w<128><<<128, 256, 0, stream>>>(W_l1, W_r1, b_l1, b_r1, WT1, bc1);
    prep_w<256><<<256, 256, 0, stream>>>(W_l2, W_r2, b_l2, b_r2, WT2, bc2);

    // conv1: one fused GEMM (l|r), MFMA
    mfma_gemm<128><<<dim3(196, 4), 256, 0, stream>>>(xb, WT1, bc1, xl1, xr1);
    gat_aggregate<64><<<NNODES, 128, 0, stream>>>(xl1, xr1, att1, offs, esrc, o1, bias2, 0);

    // bn1 + relu (-> bf16 hbuf, GEMM2 input)
    bn_stats<128><<<128, 256, 0, stream>>>(o1, bn1s, 128);
    bn1_finalize<<<1, 128, 0, stream>>>(bn1s, gamma1, beta1, ss1);
    bn_apply_relu<<<(NNODES * 64 + 255) / 256, 256, 0, stream>>>(o1, ss1, hbuf);

    // conv2
    mfma_gemm<256><<<dim3(196, 8), 256, 0, stream>>>(hbuf, WT2, bc2, xl2, xr2);
    gat_aggregate<128><<<NNODES, 128, 0, stream>>>(xl2, xr2, att2, offs, esrc, o2, bias2, 1);

    // bn2 (cols 0..63, affine=False) + softplus (cols 64..127)
    bn_stats<64><<<128, 256, 0, stream>>>(o2, bn2s, 128);
    bn2_finalize<<<1, 64, 0, stream>>>(bn2s, ms2);
    final_out<<<(NNODES * 128 + 255) / 256, 256, 0, stream>>>(o2, ms2, out);
}

// Round 6
// 514.056 us; speedup vs baseline: 2.2360x; 1.0336x over previous
//
#include <hip/hip_runtime.h>
#include <hip/hip_bf16.h>
#include <math.h>

#define NNODES 50000
#define NEDGES 800000
#define EPTOT  (NEDGES + NNODES)   // 850000 edges incl self-loops
#define NEG_SLOPE 0.2f
#define BN_EPS 1e-5f
#define LOG2E 1.44269504088896f

typedef __hip_bfloat16 bf16;
typedef __attribute__((ext_vector_type(8))) short short8;
typedef __attribute__((ext_vector_type(4))) float f32x4;
typedef __attribute__((ext_vector_type(2))) float f32x2;

__device__ __forceinline__ float us2f(unsigned short u){
    union { unsigned int i; float f; } v; v.i = ((unsigned int)u) << 16; return v.f;
}
__device__ __forceinline__ unsigned short f2us(float f){
    return (unsigned short)(__bfloat16_as_ushort(__float2bfloat16(f)));
}
// bf16 pair (one dword) -> two fp32 in 2 instructions
__device__ __forceinline__ f32x2 unpk(unsigned int w){
    union { unsigned int u; float f; } lo, hi;
    lo.u = w << 16; hi.u = w & 0xffff0000u;
    f32x2 r; r.x = lo.f; r.y = hi.f; return r;
}
__device__ __forceinline__ f32x2 pkmax(f32x2 a, f32x2 b){
#if __has_builtin(__builtin_elementwise_max)
    return __builtin_elementwise_max(a, b);
#else
    f32x2 r; r.x = fmaxf(a.x, b.x); r.y = fmaxf(a.y, b.y); return r;
#endif
}
__device__ __forceinline__ unsigned int pack2(float a, float b){
    return (unsigned int)f2us(a) | ((unsigned int)f2us(b) << 16);
}

// ---------------- CSR build ----------------

__global__ void count_deg(const int* __restrict__ ei, int* __restrict__ deg){
    int e = blockIdx.x * blockDim.x + threadIdx.x;
    if (e >= EPTOT) return;
    int dst = (e < NEDGES) ? ei[NEDGES + e] : (e - NEDGES);
    atomicAdd(&deg[dst], 1);
}

__global__ void scan1(const int* __restrict__ deg, int* __restrict__ offs, int* __restrict__ bsum){
    __shared__ int s[1024];
    int t = threadIdx.x;
    int i = blockIdx.x * 1024 + t;
    int v = (i < NNODES) ? deg[i] : 0;
    s[t] = v;
    for (int o = 1; o < 1024; o <<= 1){
        __syncthreads();
        int x = (t >= o) ? s[t - o] : 0;
        __syncthreads();
        s[t] += x;
    }
    if (i < NNODES) offs[i] = s[t] - v;     // exclusive, block-local
    if (t == 1023) bsum[blockIdx.x] = s[1023];
}

__global__ void scan2(const int* __restrict__ bsum, int* __restrict__ bbase, int* __restrict__ offs){
    if (threadIdx.x == 0 && blockIdx.x == 0){
        int run = 0;
        for (int b = 0; b < 49; ++b){ bbase[b] = run; run += bsum[b]; }
        offs[NNODES] = EPTOT;
    }
}

__global__ void scan3(int* __restrict__ offs, const int* __restrict__ bbase, int* __restrict__ cursor){
    int i = blockIdx.x * 1024 + threadIdx.x;
    if (i < NNODES){
        int v = offs[i] + bbase[blockIdx.x];
        offs[i] = v;
        cursor[i] = v;
    }
}

__global__ void scatter_edges(const int* __restrict__ ei, int* __restrict__ cursor, int* __restrict__ esrc){
    int e = blockIdx.x * blockDim.x + threadIdx.x;
    if (e >= EPTOT) return;
    int s, d;
    if (e < NEDGES){ s = ei[e]; d = ei[NEDGES + e]; } else { s = d = e - NEDGES; }
    int pos = atomicAdd(&cursor[d], 1);
    esrc[pos] = s;
}

// ---------------- dtype prep ----------------

__global__ void to_bf16_pack(const float* __restrict__ in, unsigned int* __restrict__ out, int n2){
    int i = blockIdx.x * blockDim.x + threadIdx.x;
    if (i >= n2) return;
    float2 v = ((const float2*)in)[i];
    out[i] = pack2(v.x, v.y);
}

// W[128][DTOT] fp32 (l and r) -> WT[2*DTOT][128] bf16 (transposed, l rows then r rows)
template<int DTOT>
__global__ void prep_w(const float* __restrict__ Wl, const float* __restrict__ Wr,
                       const float* __restrict__ bl, const float* __restrict__ br,
                       bf16* __restrict__ WT, float* __restrict__ biascat){
    int i = blockIdx.x * 256 + threadIdx.x;     // over 2*DTOT*128
    if (i >= 2 * DTOT * 128) return;
    int r = i >> 7;           // output row = weight column (0..2*DTOT)
    int k = i & 127;
    const float* W = (r < DTOT) ? Wl : Wr;
    int c = (r < DTOT) ? r : r - DTOT;
    WT[i] = __float2bfloat16(W[k * DTOT + c]);
    if (k == 0) biascat[r] = (r < DTOT) ? bl[c] : br[c];
}

// ---------------- MFMA GEMM: [M x 128] @ [128 x 2*DTOT] -> xl,xr [M x DTOT] bf16 ----------------

template<int DTOT>
__global__ __launch_bounds__(256) void mfma_gemm(
    const bf16* __restrict__ A, const bf16* __restrict__ WT,
    const float* __restrict__ biascat,
    bf16* __restrict__ xl, bf16* __restrict__ xr)
{
    int wave = threadIdx.x >> 6;
    int lane = threadIdx.x & 63;
    int quad = lane >> 4;
    int l16  = lane & 15;
    int m0 = blockIdx.x * 256 + wave * 64;
    int n0 = blockIdx.y * 64;

    f32x4 acc[4][4] = {};
    const short* Ap = (const short*)A;
    const short* Bp = (const short*)WT;

    #pragma unroll
    for (int k0 = 0; k0 < 128; k0 += 32){
        short8 af[4], bfr[4];
        #pragma unroll
        for (int mt = 0; mt < 4; ++mt){
            int m = m0 + mt * 16 + l16;
            m = (m < NNODES) ? m : (NNODES - 1);    // clamp; garbage rows never stored
            af[mt] = *(const short8*)(Ap + (size_t)m * 128 + k0 + quad * 8);
        }
        #pragma unroll
        for (int nt = 0; nt < 4; ++nt){
            int n = n0 + nt * 16 + l16;
            bfr[nt] = *(const short8*)(Bp + (size_t)n * 128 + k0 + quad * 8);
        }
        #pragma unroll
        for (int mt = 0; mt < 4; ++mt)
            #pragma unroll
            for (int nt = 0; nt < 4; ++nt)
                acc[mt][nt] = __builtin_amdgcn_mfma_f32_16x16x32_bf16(af[mt], bfr[nt], acc[mt][nt], 0, 0, 0);
    }

    #pragma unroll
    for (int nt = 0; nt < 4; ++nt){
        int n = n0 + nt * 16 + l16;
        float bi = biascat[n];
        bf16* outp = (n < DTOT) ? xl : xr;
        int c = (n < DTOT) ? n : n - DTOT;
        #pragma unroll
        for (int mt = 0; mt < 4; ++mt)
            #pragma unroll
            for (int r = 0; r < 4; ++r){
                int m = m0 + mt * 16 + quad * 4 + r;
                if (m < NNODES)
                    outp[(size_t)m * DTOT + c] = __float2bfloat16(acc[mt][nt][r] + bi);
            }
    }
}

// ---------------- GATv2 aggregation: multi-edge waves, packed f32 math ----------------
// Block = node, 128 threads = 2 waves, wave = head. Group g = lane/G owns edge slot g,
// chunk cl = lane%G owns 8 contiguous channels (one 16B load). Dword unpack via
// shl/and; channel math in f32x2 (v_pk_* on gfx950). No max-tracking (logits bounded,
// validated r5). Layer1 (!MEAN) writes packed bf16; layer2 (MEAN) writes fp32.

template<int C, bool MEAN>
__global__ __launch_bounds__(128) void gat_aggregate(
    const bf16* __restrict__ xl, const bf16* __restrict__ xr,
    const float* __restrict__ att, const int* __restrict__ offs,
    const int* __restrict__ esrc, void* __restrict__ outv,
    const float* __restrict__ bias2)
{
    constexpr int G  = C / 8;        // lanes per edge: 8 (C=64) / 16 (C=128)
    constexpr int E  = 64 / G;       // edges per iter: 8 / 4
    constexpr int HC = 2 * C;
    __shared__ float tmp[HC];
    int n    = blockIdx.x;
    int lane = threadIdx.x & 63;
    int head = threadIdx.x >> 6;
    int g    = lane / G;
    int cl   = lane % G;
    int rowoff = head * (C * 2) + cl * 16;     // byte offset within a row
    const char* xlb = (const char*)xl;

    uint4 xw = *(const uint4*)((const char*)xr + (size_t)n * (HC * 2) + rowoff);
    f32x2 xr0 = unpk(xw.x), xr1 = unpk(xw.y), xr2v = unpk(xw.z), xr3 = unpk(xw.w);
    const float* ap = att + head * C + cl * 8;
    f32x2 av0 = {ap[0] * LOG2E, ap[1] * LOG2E};
    f32x2 av1 = {ap[2] * LOG2E, ap[3] * LOG2E};
    f32x2 av2 = {ap[4] * LOG2E, ap[5] * LOG2E};
    f32x2 av3 = {ap[6] * LOG2E, ap[7] * LOG2E};

    int e0 = offs[n], e1 = offs[n + 1];

    float den = 0.f;
    f32x2 a0 = {0.f,0.f}, a1 = {0.f,0.f}, a2 = {0.f,0.f}, a3 = {0.f,0.f};
    for (int p0 = e0; p0 < e1; p0 += E){
        int p = p0 + g;
        float maskadd = (p < e1) ? 0.f : -1e30f;       // group-uniform
        int s = esrc[(p < e1) ? p : (e1 - 1)];
        uint4 w = *(const uint4*)(xlb + (size_t)s * (HC * 2) + rowoff);
        f32x2 x0 = unpk(w.x), x1 = unpk(w.y), x2 = unpk(w.z), x3 = unpk(w.w);
        f32x2 u0 = x0 + xr0, u1 = x1 + xr1, u2 = x2 + xr2v, u3 = x3 + xr3;
        f32x2 l0 = pkmax(u0, u0 * NEG_SLOPE), l1 = pkmax(u1, u1 * NEG_SLOPE);
        f32x2 l2 = pkmax(u2, u2 * NEG_SLOPE), l3 = pkmax(u3, u3 * NEG_SLOPE);
        f32x2 pp = l0 * av0;
        pp += l1 * av1; pp += l2 * av2; pp += l3 * av3;
        float part = pp.x + pp.y;
        #pragma unroll
        for (int mask = G / 2; mask >= 1; mask >>= 1)
            part += __shfl_xor(part, mask, 64);
        float ex = exp2f(part + maskadd);              // 0 for tail slots
        den += ex;
        f32x2 ex2 = {ex, ex};
        a0 += ex2 * x0; a1 += ex2 * x1; a2 += ex2 * x2; a3 += ex2 * x3;
    }

    // merge the E group-partials
    #pragma unroll
    for (int mask = G; mask < 64; mask <<= 1){
        den  += __shfl_xor(den, mask, 64);
        a0.x += __shfl_xor(a0.x, mask, 64); a0.y += __shfl_xor(a0.y, mask, 64);
        a1.x += __shfl_xor(a1.x, mask, 64); a1.y += __shfl_xor(a1.y, mask, 64);
        a2.x += __shfl_xor(a2.x, mask, 64); a2.y += __shfl_xor(a2.y, mask, 64);
        a3.x += __shfl_xor(a3.x, mask, 64); a3.y += __shfl_xor(a3.y, mask, 64);
    }
    float inv = 1.f / den;

    if (!MEAN){
        if (g == 0){
            uint4 o;
            o.x = pack2(a0.x * inv, a0.y * inv);
            o.y = pack2(a1.x * inv, a1.y * inv);
            o.z = pack2(a2.x * inv, a2.y * inv);
            o.w = pack2(a3.x * inv, a3.y * inv);
            *(uint4*)((char*)outv + (size_t)n * (HC * 2) + rowoff) = o;
        }
    } else {
        if (g == 0){
            float* tp = tmp + head * C + cl * 8;
            tp[0] = a0.x * inv; tp[1] = a0.y * inv;
            tp[2] = a1.x * inv; tp[3] = a1.y * inv;
            tp[4] = a2.x * inv; tp[5] = a2.y * inv;
            tp[6] = a3.x * inv; tp[7] = a3.y * inv;
        }
        __syncthreads();
        if (head == 0 && g == 0){
            float* outp = (float*)outv + (size_t)n * C + cl * 8;
            #pragma unroll
            for (int v = 0; v < 8; ++v){
                int c = cl * 8 + v;
                outp[v] = 0.5f * (tmp[c] + tmp[C + c]) + bias2[c];
            }
        }
    }
}

// ---------------- BatchNorm ----------------

// stats over packed-bf16 matrix [N][128]
__global__ void bn_stats_bf16(const unsigned int* __restrict__ x, float* __restrict__ sums){
    __shared__ float ls[1024];
    int t = threadIdx.x;              // 256 threads
    int c2 = t & 63;                  // dword column (covers ch 2*c2, 2*c2+1)
    int rg = t >> 6;                  // 4 row groups
    float s0 = 0.f, q0 = 0.f, s1 = 0.f, q1 = 0.f;
    for (int r = blockIdx.x * 4 + rg; r < NNODES; r += gridDim.x * 4){
        f32x2 v = unpk(x[(size_t)r * 64 + c2]);
        s0 += v.x; q0 += v.x * v.x;
        s1 += v.y; q1 += v.y * v.y;
    }
    ls[t] = s0; ls[256 + t] = q0; ls[512 + t] = s1; ls[768 + t] = q1;
    __syncthreads();
    if (rg == 0){
        for (int g = 1; g < 4; ++g){
            s0 += ls[g * 64 + c2];       q0 += ls[256 + g * 64 + c2];
            s1 += ls[512 + g * 64 + c2]; q1 += ls[768 + g * 64 + c2];
        }
        atomicAdd(&sums[2 * c2], s0);
        atomicAdd(&sums[128 + 2 * c2], q0);
        atomicAdd(&sums[2 * c2 + 1], s1);
        atomicAdd(&sums[128 + 2 * c2 + 1], q1);
    }
}

template<int COLS>
__global__ void bn_stats(const float* __restrict__ x, float* __restrict__ sums, int stride){
    __shared__ float ls[512];
    int t = threadIdx.x;              // 256 threads
    int col = t % COLS;
    int rg  = t / COLS;
    const int RG = 256 / COLS;
    float s = 0.f, q = 0.f;
    for (int r = blockIdx.x * RG + rg; r < NNODES; r += gridDim.x * RG){
        float v = x[(size_t)r * stride + col];
        s += v; q += v * v;
    }
    ls[t] = s; ls[256 + t] = q;
    __syncthreads();
    if (rg == 0){
        for (int g = 1; g < RG; ++g){ s += ls[g * COLS + col]; q += ls[256 + g * COLS + col]; }
        atomicAdd(&sums[col], s);
        atomicAdd(&sums[COLS + col], q);
    }
}

__global__ void bn1_finalize(const float* __restrict__ sums, const float* __restrict__ gamma,
                             const float* __restrict__ beta, float* __restrict__ ss){
    int c = threadIdx.x;              // 128
    float mu  = sums[c] / (float)NNODES;
    float var = sums[128 + c] / (float)NNODES - mu * mu;
    float sc  = gamma[c] * rsqrtf(var + BN_EPS);
    ss[c]       = sc;
    ss[128 + c] = beta[c] - mu * sc;
}

// o1 packed bf16 -> BN+ReLU -> hbuf packed bf16
__global__ void bn_apply_relu(const unsigned int* __restrict__ o1, const float* __restrict__ ss,
                              unsigned int* __restrict__ h){
    int i = blockIdx.x * blockDim.x + threadIdx.x;
    if (i >= NNODES * 64) return;
    int c2 = i & 63;
    f32x2 v = unpk(o1[i]);
    float v0 = v.x * ss[2 * c2]     + ss[128 + 2 * c2];
    float v1 = v.y * ss[2 * c2 + 1] + ss[128 + 2 * c2 + 1];
    h[i] = pack2(v0 > 0.f ? v0 : 0.f, v1 > 0.f ? v1 : 0.f);
}

__global__ void bn2_finalize(const float* __restrict__ sums, float* __restrict__ ms){
    int c = threadIdx.x;              // 64
    float mu  = sums[c] / (float)NNODES;
    float var = sums[64 + c] / (float)NNODES - mu * mu;
    ms[c]      = mu;
    ms[64 + c] = rsqrtf(var + BN_EPS);
}

__global__ void final_out(const float* __restrict__ o2, const float* __restrict__ ms,
                          float* __restrict__ out){
    int i = blockIdx.x * blockDim.x + threadIdx.x;
    if (i >= NNODES * 128) return;
    int c = i & 127;
    float v = o2[i];
    float r;
    if (c < 64){
        r = (v - ms[c]) * ms[64 + c];           // BN, affine=False
    } else {
        r = (v > 20.f) ? v : log1pf(__expf(v)); // softplus
    }
    out[i] = r;
}

// ---------------- launch ----------------

extern "C" void kernel_launch(void* const* d_in, const int* in_sizes, int n_in,
                              void* d_out, int out_size, void* d_ws, size_t ws_size,
                              hipStream_t stream) {
    const float* x     = (const float*)d_in[0];
    const int*   ei    = (const int*)d_in[1];
    const float* W_l1  = (const float*)d_in[2];
    const float* b_l1  = (const float*)d_in[3];
    const float* W_r1  = (const float*)d_in[4];
    const float* b_r1  = (const float*)d_in[5];
    const float* att1  = (const float*)d_in[6];
    // d_in[7] = bias1: cancels through BN1 (constant per-column shift) -> unused
    const float* gamma1 = (const float*)d_in[8];
    const float* beta1  = (const float*)d_in[9];
    const float* W_l2  = (const float*)d_in[10];
    const float* b_l2  = (const float*)d_in[11];
    const float* W_r2  = (const float*)d_in[12];
    const float* b_r2  = (const float*)d_in[13];
    const float* att2  = (const float*)d_in[14];
    const float* bias2 = (const float*)d_in[15];
    float* out = (float*)d_out;

    char* w = (char*)d_ws;
    size_t off = 0;
    auto alloc = [&](size_t bytes) -> void* {
        void* p = w + off;
        off += (bytes + 255) & ~(size_t)255;
        return p;
    };
    const size_t NF  = (size_t)NNODES * 128 * 4;   // 25.6 MB fp32
    bf16*  xb    = (bf16*) alloc(NF / 2);          // x in bf16 [N][128]
    bf16*  xl1   = (bf16*) alloc(NF / 2);          // N x 128 bf16
    bf16*  xr1   = (bf16*) alloc(NF / 2);
    bf16*  xl2   = (bf16*) alloc(NF);              // N x 256 bf16
    bf16*  xr2   = (bf16*) alloc(NF);
    bf16*  hbuf  = (bf16*) alloc(NF / 2);          // N x 128 bf16
    unsigned int* o1 = (unsigned int*)alloc(NF / 2);  // N x 128 bf16 (packed)
    float* o2    = (float*)alloc(NF);
    bf16*  WT1   = (bf16*) alloc(256 * 128 * 2);
    bf16*  WT2   = (bf16*) alloc(512 * 128 * 2);
    float* bc1   = (float*)alloc(256 * 4);
    float* bc2   = (float*)alloc(512 * 4);
    int*   offs   = (int*)  alloc((size_t)(NNODES + 1) * 4);
    int*   cursor = (int*)  alloc((size_t)NNODES * 4);
    int*   deg    = (int*)  alloc((size_t)NNODES * 4);
    int*   esrc   = (int*)  alloc((size_t)EPTOT * 4);
    int*   bsum   = (int*)  alloc(64 * 4);
    int*   bbase  = (int*)  alloc(64 * 4);
    float* bnsums = (float*)alloc(384 * 4);   // bn1: 256 (sum|sq), bn2: 128 (sum|sq)
    float* ss1    = (float*)alloc(256 * 4);   // bn1 scale|shift
    float* ms2    = (float*)alloc(128 * 4);   // bn2 mu|rsqrt
    float* bn1s = bnsums;
    float* bn2s = bnsums + 256;

    hipMemsetAsync(deg, 0, (size_t)NNODES * 4, stream);
    hipMemsetAsync(bnsums, 0, 384 * 4, stream);

    // CSR by destination
    count_deg<<<(EPTOT + 255) / 256, 256, 0, stream>>>(ei, deg);
    scan1<<<49, 1024, 0, stream>>>(deg, offs, bsum);
    scan2<<<1, 64, 0, stream>>>(bsum, bbase, offs);
    scan3<<<49, 1024, 0, stream>>>(offs, bbase, cursor);
    scatter_edges<<<(EPTOT + 255) / 256, 256, 0, stream>>>(ei, cursor, esrc);

    // dtype prep
    to_bf16_pack<<<(NNODES * 64 + 255) / 256, 256, 0, stream>>>(x, (unsigned int*)xb, NNODES * 64);
    prep_w<128><<<128, 256, 0, stream>>>(W_l1, W_r1, b_l1, b_r1, WT1, bc1);
    prep_w<256><<<256, 256, 0, stream>>>(W_l2, W_r2, b_l2, b_r2, WT2, bc2);

    // conv1: one fused GEMM (l|r), MFMA
    mfma_gemm<128><<<dim3(196, 4), 256, 0, stream>>>(xb, WT1, bc1, xl1, xr1);
    gat_aggregate<64, false><<<NNODES, 128, 0, stream>>>(xl1, xr1, att1, offs, esrc, o1, bias2);

    // bn1 + relu (bf16 in -> bf16 hbuf)
    bn_stats_bf16<<<128, 256, 0, stream>>>(o1, bn1s);
    bn1_finalize<<<1, 128, 0, stream>>>(bn1s, gamma1, beta1, ss1);
    bn_apply_relu<<<(NNODES * 64 + 255) / 256, 256, 0, stream>>>(o1, ss1, (unsigned int*)hbuf);

    // conv2
    mfma_gemm<256><<<dim3(196, 8), 256, 0, stream>>>(hbuf, WT2, bc2, xl2, xr2);
    gat_aggregate<128, true><<<NNODES, 128, 0, stream>>>(xl2, xr2, att2, offs, esrc, o2, bias2);

    // bn2 (cols 0..63, affine=False) + softplus (cols 64..127)
    bn_stats<64><<<128, 256, 0, stream>>>(o2, bn2s, 128);
    bn2_finalize<<<1, 64, 0, stream>>>(bn2s, ms2);
    final_out<<<(NNODES * 128 + 255) / 256, 256, 0, stream>>>(o2, ms2, out);
}